// Round 1
// baseline (459.986 us; speedup 1.0000x reference)
//
#include <hip/hip_runtime.h>
#include <cstdint>
#include <cstddef>

// Binarized basic block on MI355X.
// Key fact: |acc| <= 9*128 = 1152 < THRESH=8000, so the per-partial-sum clip
// in psum_conv3x3 never binds -> both convs are exact int convolutions of
// sign() values. We do int8 implicit GEMM via mfma_i32_16x16x64_i8 and make
// every float op bit-exact vs the numpy fp32 reference (no FMA contraction).

typedef int v4i __attribute__((ext_vector_type(4)));

constexpr int B = 64, C = 128, H = 56, W = 56;
constexpr int HP = H + 2, WP = W + 2;      // zero-padded spatial
constexpr int PIX = H * W;                 // 3136
constexpr int M = B * H * W;               // 200704 = 3136 * 64 (no tail)

// workspace layout (bytes)
constexpr size_t XS_BYTES = (size_t)B * HP * WP * C;   // 27,557,888
constexpr size_t XS1_OFF = 0;
constexpr size_t XS2_OFF = XS_BYTES;
constexpr size_t WF_BYTES = 9 * 2 * 8 * 64 * 16;       // 147,456
constexpr size_t WF1_OFF = 2 * XS_BYTES;
constexpr size_t WF2_OFF = WF1_OFF + WF_BYTES;
constexpr size_t BNP_OFF = WF2_OFF + WF_BYTES;         // 4*128 floats

// ---------------------------------------------------------------------------
// sign(x) -> padded NHWC int8. One thread per pixel; reads coalesced along w
// for each channel; writes its 128-byte channel vector.
__global__ __launch_bounds__(256) void prep_x(const float* __restrict__ x,
                                              int8_t* __restrict__ xs) {
    int m = blockIdx.x * 256 + threadIdx.x;
    if (m >= M) return;
    int w = m % W; int t = m / W; int h = t % H; int b = t / H;
    const float* xp = x + (size_t)b * C * PIX + h * W + w;
    size_t obase = ((size_t)(b * HP + h + 1) * WP + (w + 1)) * C;
    uint32_t buf[32];
#pragma unroll
    for (int c4 = 0; c4 < 32; ++c4) {
        uint32_t v = 0;
#pragma unroll
        for (int j = 0; j < 4; ++j) {
            float f = xp[(size_t)(c4 * 4 + j) * PIX];
            int sg = (f > 0.f) - (f < 0.f);
            v |= ((uint32_t)(uint8_t)(int8_t)sg) << (8 * j);
        }
        buf[c4] = v;
    }
    uint32_t* o = (uint32_t*)(xs + obase);
#pragma unroll
    for (int c4 = 0; c4 < 32; ++c4) o[c4] = buf[c4];
}

// ---------------------------------------------------------------------------
// Binarize weights into MFMA B-fragment order:
//   wf[(tap*2+kh)*8+nsub][lane][j] = sign(w[o=nsub*16+(lane&15)]
//                                          [c=kh*64+(lane>>4)*16+j][r][s])
// Also compute BN inv/shift tables exactly as numpy fp32 does.
__global__ __launch_bounds__(256) void prep_w(
    const float* __restrict__ w1, const float* __restrict__ w2,
    const float* __restrict__ g1, const float* __restrict__ be1,
    const float* __restrict__ mu1, const float* __restrict__ va1,
    const float* __restrict__ g2, const float* __restrict__ be2,
    const float* __restrict__ mu2, const float* __restrict__ va2,
    int8_t* __restrict__ wf1, int8_t* __restrict__ wf2,
    float* __restrict__ bnp) {
    int t = blockIdx.x * 256 + threadIdx.x;
    if (t < 256) {
        int o = t & 127;
        if (t < 128) {
            float inv = g1[o] / sqrtf(va1[o] + 1e-5f);
            bnp[o]       = inv;
            bnp[128 + o] = __fsub_rn(be1[o], __fmul_rn(mu1[o], inv));
        } else {
            float inv = g2[o] / sqrtf(va2[o] + 1e-5f);
            bnp[256 + o] = inv;
            bnp[384 + o] = __fsub_rn(be2[o], __fmul_rn(mu2[o], inv));
        }
    }
    if (t >= 2 * 9 * 2 * 8 * 64) return;
    int lane = t & 63;
    int nsub = (t >> 6) & 7;
    int kh   = (t >> 9) & 1;
    int tap  = (t >> 10) % 9;
    int which = (t >> 10) / 9;
    const float* w = which ? w2 : w1;
    int8_t* wf = which ? wf2 : wf1;
    int o = nsub * 16 + (lane & 15);
    int cbase = kh * 64 + (lane >> 4) * 16;
    int r = tap / 3, s = tap % 3;
    int8_t frag[16];
#pragma unroll
    for (int j = 0; j < 16; ++j) {
        float f = w[((size_t)(o * C + cbase + j) * 3 + r) * 3 + s];
        frag[j] = (int8_t)((f > 0.f) - (f < 0.f));
    }
    *(v4i*)(wf + (size_t)(((tap * 2 + kh) * 8 + nsub) * 64 + lane) * 16) =
        *(const v4i*)frag;
}

// ---------------------------------------------------------------------------
// Binary conv via int8 MFMA implicit GEMM.
// Block = 64 M-rows x 128 O. 4 waves; wave wv owns M rows [wv*16, wv*16+16),
// 8 accumulator tiles of 16x16 covering all 128 output channels.
// PHASE 1: epilogue = sign(BN1(conv)) -> padded NHWC int8.
// PHASE 2: epilogue = clip(BN2(conv) + residual, -1, 1) -> NCHW fp32.
template <int PHASE>
__global__ __launch_bounds__(256) void conv_bin(
    const int8_t* __restrict__ xs,     // padded NHWC signs
    const int8_t* __restrict__ wf,     // fragment-ordered weights
    const float* __restrict__ bnp,     // bn tables
    const float* __restrict__ xres,    // residual (PHASE 2)
    int8_t* __restrict__ xs_next,      // PHASE 1 out
    float* __restrict__ out)           // PHASE 2 out
{
    int lane = threadIdx.x & 63;
    int wv   = threadIdx.x >> 6;
    int quad = lane >> 4;
    int l15  = lane & 15;
    int mbase = blockIdx.x * 64 + wv * 16;

    // A-operand base: lane l holds X[m = mbase+l15][c = quad*16 + j(0..15)]
    // (+ kh*64 per K-half, + (r*WP+s)*C per tap). Padded window: center (h,w)
    // -> padded rows h..h+2, cols w..w+2.
    {
    }
    int ma = mbase + l15;
    int wa = ma % W; int ta = ma / W; int ha = ta % H; int ba = ta / H;
    size_t abase = ((size_t)(ba * HP + ha) * WP + wa) * C + (size_t)quad * 16;

    v4i acc[8];
#pragma unroll
    for (int n = 0; n < 8; ++n) acc[n] = (v4i)0;

#pragma unroll
    for (int tap = 0; tap < 9; ++tap) {
        int r = tap / 3, s = tap % 3;
        size_t aoff = abase + (size_t)(r * WP + s) * C;
#pragma unroll
        for (int kh = 0; kh < 2; ++kh) {
            v4i a = *(const v4i*)(xs + aoff + kh * 64);
            const int8_t* wb = wf + (size_t)((tap * 2 + kh) * 8) * 64 * 16;
#pragma unroll
            for (int n = 0; n < 8; ++n) {
                v4i bfrag = *(const v4i*)(wb + (size_t)(n * 64 + lane) * 16);
                acc[n] = __builtin_amdgcn_mfma_i32_16x16x64_i8(a, bfrag, acc[n], 0, 0, 0);
            }
        }
    }

    // D layout: col(o) = lane&15, row(m) = quad*4 + reg.
    int prow[4];   // PHASE 1: padded byte base for intermediate
    int pixo[4];   // PHASE 2: b*C*PIX + h*W + w (add o*PIX)
#pragma unroll
    for (int i = 0; i < 4; ++i) {
        int m = mbase + quad * 4 + i;
        int w_ = m % W; int t_ = m / W; int h_ = t_ % H; int b_ = t_ / H;
        prow[i] = ((b_ * HP + h_ + 1) * WP + (w_ + 1)) * C;
        pixo[i] = b_ * C * PIX + h_ * W + w_;
    }

#pragma unroll
    for (int n = 0; n < 8; ++n) {
        int o = n * 16 + l15;
        float inv, tt;
        if (PHASE == 1) { inv = bnp[o];       tt = bnp[128 + o]; }
        else            { inv = bnp[256 + o]; tt = bnp[384 + o]; }
#pragma unroll
        for (int i = 0; i < 4; ++i) {
            float v = (float)acc[n][i];
            float y = __fadd_rn(__fmul_rn(v, inv), tt);  // numpy: v*inv + t, no fma
            if (PHASE == 1) {
                // clip(-1,1) preserves sign; binarize = sign(y)
                xs_next[(size_t)prow[i] + o] = (int8_t)((y > 0.f) - (y < 0.f));
            } else {
                size_t idx = (size_t)pixo[i] + (size_t)o * PIX;
                float z = __fadd_rn(y, xres[idx]);
                z = fminf(fmaxf(z, -1.f), 1.f);
                out[idx] = z;
            }
        }
    }
}

// ---------------------------------------------------------------------------
extern "C" void kernel_launch(void* const* d_in, const int* in_sizes, int n_in,
                              void* d_out, int out_size, void* d_ws, size_t ws_size,
                              hipStream_t stream) {
    const float* x   = (const float*)d_in[0];
    const float* w1  = (const float*)d_in[1];
    const float* w2  = (const float*)d_in[2];
    const float* g1  = (const float*)d_in[3];
    const float* be1 = (const float*)d_in[4];
    const float* mu1 = (const float*)d_in[5];
    const float* va1 = (const float*)d_in[6];
    const float* g2  = (const float*)d_in[7];
    const float* be2 = (const float*)d_in[8];
    const float* mu2 = (const float*)d_in[9];
    const float* va2 = (const float*)d_in[10];

    int8_t* ws  = (int8_t*)d_ws;
    int8_t* xs1 = ws + XS1_OFF;
    int8_t* xs2 = ws + XS2_OFF;
    int8_t* wf1 = ws + WF1_OFF;
    int8_t* wf2 = ws + WF2_OFF;
    float*  bnp = (float*)(ws + BNP_OFF);

    // zero halos (and interiors; interiors are overwritten)
    hipMemsetAsync(xs1, 0, 2 * XS_BYTES, stream);

    prep_x<<<(M + 255) / 256, 256, 0, stream>>>(x, xs1);
    prep_w<<<(2 * 9 * 2 * 8 * 64 + 255) / 256, 256, 0, stream>>>(
        w1, w2, g1, be1, mu1, va1, g2, be2, mu2, va2, wf1, wf2, bnp);

    conv_bin<1><<<M / 64, 256, 0, stream>>>(xs1, wf1, bnp, nullptr, xs2, nullptr);
    conv_bin<2><<<M / 64, 256, 0, stream>>>(xs2, wf2, bnp, x, nullptr, (float*)d_out);
}

// Round 2
// 421.746 us; speedup vs baseline: 1.0907x; 1.0907x over previous
//
#include <hip/hip_runtime.h>
#include <cstdint>
#include <cstddef>

// Binarized basic block on MI355X.
// |acc| <= 9*128 = 1152 < THRESH=8000, so the per-partial-sum clip never
// binds -> both convs are exact int convolutions of sign() values.
// int8 implicit GEMM via mfma_i32_16x16x64_i8; all float ops bit-exact vs
// numpy fp32 (explicit __fmul_rn/__fadd_rn, no FMA contraction).
//
// R2: LDS-staged double-buffered weights (8KB/step), 32 M-rows/wave,
// A+W prefetch one step ahead, halo-only zeroing.

typedef int v4i __attribute__((ext_vector_type(4)));

constexpr int B = 64, C = 128, H = 56, W = 56;
constexpr int HP = H + 2, WP = W + 2;      // zero-padded spatial
constexpr int PIX = H * W;                 // 3136
constexpr int M = B * H * W;               // 200704 = 1568 * 128

// workspace layout (bytes)
constexpr size_t XS_BYTES = (size_t)B * HP * WP * C;   // 27,557,888
constexpr size_t XS1_OFF = 0;
constexpr size_t XS2_OFF = XS_BYTES;
constexpr size_t WF_BYTES = 18 * 8 * 64 * 16;          // 147,456 (18 steps x 8KB)
constexpr size_t WF1_OFF = 2 * XS_BYTES;
constexpr size_t WF2_OFF = WF1_OFF + WF_BYTES;
constexpr size_t BNP_OFF = WF2_OFF + WF_BYTES;         // 4*128 floats

// ---------------------------------------------------------------------------
// Zero only the padded halos of xs1/xs2 (interiors are fully overwritten by
// prep_x / conv_bin<1>). One block per image, handles both arrays.
__global__ __launch_bounds__(256) void zero_halo(int8_t* __restrict__ xs1,
                                                 int8_t* __restrict__ xs2) {
    int b = blockIdx.x;
    int t = threadIdx.x;
    size_t ib = (size_t)b * HP * WP * C;
#pragma unroll
    for (int a = 0; a < 2; ++a) {
        uint32_t* p = (uint32_t*)((a ? xs2 : xs1) + ib);
        const int ROWD = WP * C / 4;             // 1856 dwords per padded row
        // top + bottom rows
        for (int i = t; i < ROWD; i += 256) {
            p[i] = 0;
            p[(HP - 1) * ROWD + i] = 0;
        }
        // left/right columns of the 56 interior rows: 32 dwords each
        for (int i = t; i < 56 * 2 * 32; i += 256) {
            int r = i >> 6;                       // 0..55
            int side = (i >> 5) & 1;
            int j = i & 31;
            p[((r + 1) * WP + side * (WP - 1)) * (C / 4) + j] = 0;
        }
    }
}

// ---------------------------------------------------------------------------
// sign(x) -> padded NHWC int8. One thread per pixel.
__global__ __launch_bounds__(256) void prep_x(const float* __restrict__ x,
                                              int8_t* __restrict__ xs) {
    int m = blockIdx.x * 256 + threadIdx.x;
    if (m >= M) return;
    int w = m % W; int t = m / W; int h = t % H; int b = t / H;
    const float* xp = x + (size_t)b * C * PIX + h * W + w;
    size_t obase = ((size_t)(b * HP + h + 1) * WP + (w + 1)) * C;
    uint32_t buf[32];
#pragma unroll
    for (int c4 = 0; c4 < 32; ++c4) {
        uint32_t v = 0;
#pragma unroll
        for (int j = 0; j < 4; ++j) {
            float f = xp[(size_t)(c4 * 4 + j) * PIX];
            int sg = (f > 0.f) - (f < 0.f);
            v |= ((uint32_t)(uint8_t)(int8_t)sg) << (8 * j);
        }
        buf[c4] = v;
    }
    uint32_t* o = (uint32_t*)(xs + obase);
#pragma unroll
    for (int c4 = 0; c4 < 32; ++c4) o[c4] = buf[c4];
}

// ---------------------------------------------------------------------------
// Binarize weights into MFMA B-fragment order:
//   wf[((tap*2+kh)*8+nsub)*1024 + lane*16 + j] =
//     sign(w[o=nsub*16+(lane&15)][c=kh*64+(lane>>4)*16+j][r][s])
// Also BN inv/shift tables exactly as numpy fp32.
__global__ __launch_bounds__(256) void prep_w(
    const float* __restrict__ w1, const float* __restrict__ w2,
    const float* __restrict__ g1, const float* __restrict__ be1,
    const float* __restrict__ mu1, const float* __restrict__ va1,
    const float* __restrict__ g2, const float* __restrict__ be2,
    const float* __restrict__ mu2, const float* __restrict__ va2,
    int8_t* __restrict__ wf1, int8_t* __restrict__ wf2,
    float* __restrict__ bnp) {
    int t = blockIdx.x * 256 + threadIdx.x;
    if (t < 256) {
        int o = t & 127;
        if (t < 128) {
            float inv = g1[o] / sqrtf(va1[o] + 1e-5f);
            bnp[o]       = inv;
            bnp[128 + o] = __fsub_rn(be1[o], __fmul_rn(mu1[o], inv));
        } else {
            float inv = g2[o] / sqrtf(va2[o] + 1e-5f);
            bnp[256 + o] = inv;
            bnp[384 + o] = __fsub_rn(be2[o], __fmul_rn(mu2[o], inv));
        }
    }
    if (t >= 2 * 18 * 8 * 64) return;
    int lane = t & 63;
    int nsub = (t >> 6) & 7;
    int kh   = (t >> 9) & 1;
    int tap  = (t >> 10) % 9;
    int which = (t >> 10) / 9;
    const float* w = which ? w2 : w1;
    int8_t* wf = which ? wf2 : wf1;
    int o = nsub * 16 + (lane & 15);
    int cbase = kh * 64 + (lane >> 4) * 16;
    int r = tap / 3, s = tap % 3;
    int8_t frag[16];
#pragma unroll
    for (int j = 0; j < 16; ++j) {
        float f = w[((size_t)(o * C + cbase + j) * 3 + r) * 3 + s];
        frag[j] = (int8_t)((f > 0.f) - (f < 0.f));
    }
    *(v4i*)(wf + (size_t)(((tap * 2 + kh) * 8 + nsub) * 64 + lane) * 16) =
        *(const v4i*)frag;
}

// ---------------------------------------------------------------------------
// Binary conv via int8 MFMA implicit GEMM.
// Block = 256 thr (4 waves) x 128 M-rows x all 128 O.
// Wave wv owns rows [wv*32, wv*32+32) as two 16-row groups; 2x8 acc tiles.
// K-loop: 18 steps (tap*2+kh); weights double-buffered in LDS (8KB/step),
// staged cooperatively; A + W prefetched one step ahead.
// PHASE 1: epilogue = sign(BN1(conv)) -> padded NHWC int8.
// PHASE 2: epilogue = clip(BN2(conv) + residual, -1, 1) -> NCHW fp32.
template <int PHASE>
__global__ __launch_bounds__(256) void conv_bin(
    const int8_t* __restrict__ xs,     // padded NHWC signs
    const int8_t* __restrict__ wf,     // fragment-ordered weights (18*8KB)
    const float* __restrict__ bnp,     // bn tables
    const float* __restrict__ xres,    // residual (PHASE 2)
    int8_t* __restrict__ xs_next,      // PHASE 1 out
    float* __restrict__ out)           // PHASE 2 out
{
    __shared__ int8_t lds[2][8192];
    int t    = threadIdx.x;
    int lane = t & 63;
    int wv   = t >> 6;
    int quad = lane >> 4;
    int l15  = lane & 15;
    int mwave = blockIdx.x * 128 + wv * 32;

    // A-operand bases: lane holds X[m = mwave+rg*16+l15][c = quad*16 + j]
    size_t abase[2];
#pragma unroll
    for (int rg = 0; rg < 2; ++rg) {
        int ma = mwave + rg * 16 + l15;
        int wa = ma % W; int ta = ma / W; int ha = ta % H; int ba = ta / H;
        abase[rg] = ((size_t)(ba * HP + ha) * WP + wa) * C + (size_t)quad * 16;
    }

    v4i acc[2][8];
#pragma unroll
    for (int rg = 0; rg < 2; ++rg)
#pragma unroll
        for (int n = 0; n < 8; ++n) acc[rg][n] = (v4i)0;

    // prologue: stage step 0 weights, load step 0 A-frags
    {
        const v4i* g = (const v4i*)(wf + (size_t)t * 32);
        v4i s0 = g[0], s1 = g[1];
        *(v4i*)(&lds[0][t * 32])      = s0;
        *(v4i*)(&lds[0][t * 32 + 16]) = s1;
    }
    v4i a0 = *(const v4i*)(xs + abase[0]);   // step0: tap=0,kh=0 -> aoff=0
    v4i a1 = *(const v4i*)(xs + abase[1]);
    __syncthreads();

#pragma unroll
    for (int step = 0; step < 18; ++step) {
        v4i p0, p1, an0, an1;
        if (step + 1 < 18) {
            // prefetch next step's weights + A-frags
            const v4i* g = (const v4i*)(wf + (size_t)(step + 1) * 8192 + t * 32);
            p0 = g[0]; p1 = g[1];
            int ntap = (step + 1) >> 1, nkh = (step + 1) & 1;
            size_t aoff = (size_t)((ntap / 3) * WP + (ntap % 3)) * C + nkh * 64;
            an0 = *(const v4i*)(xs + abase[0] + aoff);
            an1 = *(const v4i*)(xs + abase[1] + aoff);
        }
        const int8_t* lbase = lds[step & 1];
#pragma unroll
        for (int n = 0; n < 8; ++n) {
            v4i bf = *(const v4i*)(lbase + ((size_t)n * 64 + lane) * 16);
            acc[0][n] = __builtin_amdgcn_mfma_i32_16x16x64_i8(a0, bf, acc[0][n], 0, 0, 0);
            acc[1][n] = __builtin_amdgcn_mfma_i32_16x16x64_i8(a1, bf, acc[1][n], 0, 0, 0);
        }
        if (step + 1 < 18) {
            int nb = (step + 1) & 1;
            *(v4i*)(&lds[nb][t * 32])      = p0;
            *(v4i*)(&lds[nb][t * 32 + 16]) = p1;
            a0 = an0; a1 = an1;
        }
        __syncthreads();
    }

    // Epilogue. D layout: col(o) = lane&15, row(m within 16) = quad*4 + reg.
#pragma unroll
    for (int rg = 0; rg < 2; ++rg) {
        int prow[4];   // PHASE 1: padded byte base
        int pixo[4];   // PHASE 2: b*C*PIX + h*W + w
#pragma unroll
        for (int i = 0; i < 4; ++i) {
            int m = mwave + rg * 16 + quad * 4 + i;
            int w_ = m % W; int t_ = m / W; int h_ = t_ % H; int b_ = t_ / H;
            prow[i] = ((b_ * HP + h_ + 1) * WP + (w_ + 1)) * C;
            pixo[i] = b_ * C * PIX + h_ * W + w_;
        }
#pragma unroll
        for (int n = 0; n < 8; ++n) {
            int o = n * 16 + l15;
            float inv, tt;
            if (PHASE == 1) { inv = bnp[o];       tt = bnp[128 + o]; }
            else            { inv = bnp[256 + o]; tt = bnp[384 + o]; }
#pragma unroll
            for (int i = 0; i < 4; ++i) {
                float v = (float)acc[rg][n][i];
                float y = __fadd_rn(__fmul_rn(v, inv), tt);  // numpy: no fma
                if (PHASE == 1) {
                    // clip(-1,1) preserves sign; binarize = sign(y)
                    xs_next[(size_t)prow[i] + o] = (int8_t)((y > 0.f) - (y < 0.f));
                } else {
                    size_t idx = (size_t)pixo[i] + (size_t)o * PIX;
                    float z = __fadd_rn(y, xres[idx]);
                    z = fminf(fmaxf(z, -1.f), 1.f);
                    out[idx] = z;
                }
            }
        }
    }
}

// ---------------------------------------------------------------------------
extern "C" void kernel_launch(void* const* d_in, const int* in_sizes, int n_in,
                              void* d_out, int out_size, void* d_ws, size_t ws_size,
                              hipStream_t stream) {
    const float* x   = (const float*)d_in[0];
    const float* w1  = (const float*)d_in[1];
    const float* w2  = (const float*)d_in[2];
    const float* g1  = (const float*)d_in[3];
    const float* be1 = (const float*)d_in[4];
    const float* mu1 = (const float*)d_in[5];
    const float* va1 = (const float*)d_in[6];
    const float* g2  = (const float*)d_in[7];
    const float* be2 = (const float*)d_in[8];
    const float* mu2 = (const float*)d_in[9];
    const float* va2 = (const float*)d_in[10];

    int8_t* ws  = (int8_t*)d_ws;
    int8_t* xs1 = ws + XS1_OFF;
    int8_t* xs2 = ws + XS2_OFF;
    int8_t* wf1 = ws + WF1_OFF;
    int8_t* wf2 = ws + WF2_OFF;
    float*  bnp = (float*)(ws + BNP_OFF);

    zero_halo<<<B, 256, 0, stream>>>(xs1, xs2);
    prep_x<<<(M + 255) / 256, 256, 0, stream>>>(x, xs1);
    prep_w<<<(2 * 18 * 8 * 64 + 255) / 256, 256, 0, stream>>>(
        w1, w2, g1, be1, mu1, va1, g2, be2, mu2, va2, wf1, wf2, bnp);

    conv_bin<1><<<M / 128, 256, 0, stream>>>(xs1, wf1, bnp, nullptr, xs2, nullptr);
    conv_bin<2><<<M / 128, 256, 0, stream>>>(xs2, wf2, bnp, x, nullptr, (float*)d_out);
}